// Round 12
// baseline (311.702 us; speedup 1.0000x reference)
//
#include <hip/hip_runtime.h>

// MS1: 64-layer reversible net, fused single-kernel recurrence.
//   Z += H*tanh(Y @ K_j^T + b_j[256:]);  Y += H*tanh(b_j[:256] - Z @ K_j)
// R12: B never touches LDS. B-frags load global->reg via inline-asm
// global_load_dwordx4 (cannot be sunk by the scheduler - fixes R4-R7's dead
// register pipeline), depth-2 rotating sets, consumption ordered by counted
// s_waitcnt vmcnt + sched_barrier(0). LDS keeps only the A-state all-gather
// (unavoidable: GEMM2 contracts the dim GEMM1 distributed) + bias. LDS
// traffic/CU-phase 392->~150 KB. 256 blocks x 32 rows, 512 thr (8 waves);
// wave w owns cols 32w..32w+31, both m-tiles; fp16 GEMM in, fp32 masters.
// Ledger (2 loads/tile, issue tile v+2 after FMAS(v), bias after t2):
//   entry: t0,t1 outstanding(4). KT0:WAITV(2) KT1:WAITV(3) KT2:WAITV(3)
//   KT3:WAITV(2,retires bias) KT4..7:WAITV(2); KT6/7 issue next-phase t0/t1.
//   exit: 4 outstanding = entry invariant. One raw s_barrier per phase.

typedef _Float16 f16x8 __attribute__((ext_vector_type(8)));
typedef _Float16 f16x2 __attribute__((ext_vector_type(2)));
typedef float    f32x4 __attribute__((ext_vector_type(4)));

#define H_STEP 0.015625f   // 1/64

// LDS layout in halfs (static 34816 B):
#define ST_Y   0          // Y hi: 0..8191
#define ST_Z   8192       // Z hi
#define BIASO  16384      // 8 waves x 64 f32 = 1024 halfs

__device__ __forceinline__ float fast_tanh(float x) {
    float xc = fminf(fmaxf(x, -9.0f), 9.0f);
    float t  = __builtin_amdgcn_exp2f(xc * 2.8853900817779268f); // 2x*log2(e)
    return (t - 1.0f) * __builtin_amdgcn_rcpf(t + 1.0f);
}

// state LDS index with XOR swizzle (16B-granular column rotation per row)
__device__ __forceinline__ int swz(int m, int k) {
    return (m << 8) + (k ^ ((m & 7) << 3));
}

__device__ __forceinline__ void gload4(const float* g, _Float16* l) {
    __builtin_amdgcn_global_load_lds(
        (const __attribute__((address_space(1))) unsigned int*)g,
        (__attribute__((address_space(3))) unsigned int*)l, 4, 0, 0);
}

// async 16B global->VGPR load; result valid only after our counted vmcnt wait
__device__ __forceinline__ f16x8 gload_async(const _Float16* p) {
    f16x8 r;
    asm volatile("global_load_dwordx4 %0, %1, off"
                 : "=v"(r) : "v"(p) : "memory");
    return r;
}

// ---------------- prep: K[a][b][j] -> fragment-ordered fp16 arrays ----------
// Layout: [j][kt][w 0..7][u 0..127][8 halfs]; unit u = c_local*4 + (chunk ^
// ((c_local>>1)&3)) holds B[col=32w+c_local][k=kt*32+chunk*8 ..+8].
// B1[n][k]=K[n][k][j] (Y@K^T);  B2[n][k]=K[k][n][j] (Z@K)
__global__ __launch_bounds__(256) void prep_split(
    const float* __restrict__ K,
    _Float16* __restrict__ B1h, _Float16* __restrict__ B2h)
{
    __shared__ float tile[32][33][9];
    const int a0 = (blockIdx.x & 7) << 5;
    const int b0 = ((blockIdx.x >> 3) & 7) << 5;
    const int j0 = (blockIdx.x >> 6) << 3;
    const int t = threadIdx.x;

    for (int idx = t; idx < 8192; idx += 256) {
        const int jj = idx & 7, bb = (idx >> 3) & 31, aa = idx >> 8;
        tile[aa][bb][jj] = K[((size_t)(a0 + aa) * 256 + (b0 + bb)) * 64 + (j0 + jj)];
    }
    __syncthreads();

    {
        const int w1 = a0 >> 5, kt = b0 >> 5;
        for (int idx = t; idx < 4096; idx += 256) {
            const int p = idx & 15, aa = (idx >> 4) & 31, jj = idx >> 9;
            const int kl = 2 * p, c = kl >> 3, e = kl & 7;
            const int u = aa * 4 + (c ^ ((aa >> 1) & 3));
            const size_t off = ((size_t)((j0 + jj) * 8 + kt)) * 8192 + w1 * 1024 + u * 8 + e;
            const f16x2 hv = {(_Float16)tile[aa][kl][jj], (_Float16)tile[aa][kl + 1][jj]};
            *(f16x2*)(B1h + off) = hv;
        }
    }
    {
        const int w2 = b0 >> 5, kt = a0 >> 5;
        for (int idx = t; idx < 4096; idx += 256) {
            const int p = idx & 15, bb = (idx >> 4) & 31, jj = idx >> 9;
            const int kl = 2 * p, c = kl >> 3, e = kl & 7;
            const int u = bb * 4 + (c ^ ((bb >> 1) & 3));
            const size_t off = ((size_t)((j0 + jj) * 8 + kt)) * 8192 + w2 * 1024 + u * 8 + e;
            const f16x2 hv = {(_Float16)tile[kl][bb][jj], (_Float16)tile[kl + 1][bb][jj]};
            *(f16x2*)(B2h + off) = hv;
        }
    }
}

#define MFMA16(A, B, C) __builtin_amdgcn_mfma_f32_16x16x32_f16((A), (B), (C), 0, 0, 0)
#define SBAR __builtin_amdgcn_sched_barrier(0)
#define WAITV(N) { asm volatile("s_waitcnt vmcnt(" #N ")" ::: "memory"); SBAR; }
#define WAITL(N) { asm volatile("s_waitcnt lgkmcnt(" #N ")" ::: "memory"); SBAR; }

// issue the 2 A ds_reads for k-tile PK
#define LOADA(A0, A1, PK)                                                       \
    {                                                                           \
        const int k0_ = (PK) * 32 + hi4 * 8;                                    \
        A0 = *(const f16x8*)(lds + stA + swz(l15, k0_));                        \
        A1 = *(const f16x8*)(lds + stA + swz(16 + l15, k0_));                   \
    }

#define FMAS(A0, A1, B0, B1)                                                    \
    accH00 = MFMA16(A0, B0, accH00);                                            \
    accH01 = MFMA16(A0, B1, accH01);                                            \
    accH10 = MFMA16(A1, B0, accH10);                                            \
    accH11 = MFMA16(A1, B1, accH11);

// issue B tile T (halfs offset T*8192) from array SRC into a register set
#define BLOAD(BA, BB, SRC, T)                                                   \
    BA = gload_async((SRC) + (T) * 8192 + pb0);                                 \
    BB = gload_async((SRC) + (T) * 8192 + pb1);

// one half-layer: 8 k-tiles; B in regs (depth-2), A via LDS (depth-1)
template<bool NEG>
__device__ __forceinline__ void phase(
    _Float16* lds, const int stA, const int stO,
    const _Float16* __restrict__ Bc,   // this half-layer's B array (j base)
    const _Float16* __restrict__ Bn,   // next half-layer's B array
    const float* __restrict__ biasG,   // bvec + featbase*64 + j
    float (&M)[2][2][4],
    f16x8& b0a, f16x8& b0b, f16x8& b1a, f16x8& b1b,   // B sets (live cross-phase)
    const int w, const int l15, const int hi4,
    const int pb0, const int pb1, const size_t bsrc)
{
    f32x4 accH00 = {0.f,0.f,0.f,0.f}, accH01 = {0.f,0.f,0.f,0.f};
    f32x4 accH10 = {0.f,0.f,0.f,0.f}, accH11 = {0.f,0.f,0.f,0.f};

    f16x8 ca0, ca1, na0, na1;
    LOADA(ca0, ca1, 0)

    // KT0: consume t0(set0)
    WAITV(2)
    LOADA(na0, na1, 1)
    WAITL(2)
    FMAS(ca0, ca1, b0a, b0b)
    BLOAD(b0a, b0b, Bc, 2) SBAR;
    gload4(biasG + bsrc, lds + BIASO + (w << 7));
    // KT1: consume t1(set1)
    WAITV(3)
    LOADA(ca0, ca1, 2)
    WAITL(2)
    FMAS(na0, na1, b1a, b1b)
    BLOAD(b1a, b1b, Bc, 3)
    // KT2
    WAITV(3)
    LOADA(na0, na1, 3)
    WAITL(2)
    FMAS(ca0, ca1, b0a, b0b)
    BLOAD(b0a, b0b, Bc, 4)
    // KT3 (retires bias too)
    WAITV(2)
    LOADA(ca0, ca1, 4)
    WAITL(2)
    FMAS(na0, na1, b1a, b1b)
    BLOAD(b1a, b1b, Bc, 5)
    // KT4
    WAITV(2)
    LOADA(na0, na1, 5)
    WAITL(2)
    FMAS(ca0, ca1, b0a, b0b)
    BLOAD(b0a, b0b, Bc, 6)
    // KT5
    WAITV(2)
    LOADA(ca0, ca1, 6)
    WAITL(2)
    FMAS(na0, na1, b1a, b1b)
    BLOAD(b1a, b1b, Bc, 7)
    // KT6: tail prefetch -> next phase t0
    WAITV(2)
    LOADA(na0, na1, 7)
    WAITL(2)
    FMAS(ca0, ca1, b0a, b0b)
    BLOAD(b0a, b0b, Bn, 0)
    // KT7: tail prefetch -> next phase t1
    WAITV(2)
    WAITL(0)
    FMAS(na0, na1, b1a, b1b)
    BLOAD(b1a, b1b, Bn, 1)

    // epilogue: bias from LDS, master += H*tanh(bias +/- acc), state hi to LDS
    const float* bp = (const float*)(lds + BIASO + (w << 7));
    const float bv0 = bp[l15], bv1 = bp[l15 + 16];

#pragma unroll
    for (int mt = 0; mt < 2; ++mt) {
#pragma unroll
        for (int nt = 0; nt < 2; ++nt) {
            const f32x4 s4 = (mt == 0) ? ((nt == 0) ? accH00 : accH01)
                                       : ((nt == 0) ? accH10 : accH11);
            const float bv = nt ? bv1 : bv0;
            const int n = (w << 5) + nt * 16 + l15;
#pragma unroll
            for (int q = 0; q < 4; ++q) {
                const float x = NEG ? (bv - s4[q]) : (s4[q] + bv);
                const float v = M[mt][nt][q] + H_STEP * fast_tanh(x);
                M[mt][nt][q] = v;
                const int m = mt * 16 + hi4 * 4 + q;
                lds[stO + swz(m, n)] = (_Float16)v;
            }
        }
    }
    // my state writes visible -> raw barrier (B prefetch vmcnt stays live)
    asm volatile("s_waitcnt lgkmcnt(0)" ::: "memory");
    __builtin_amdgcn_s_barrier();
    SBAR;
}

__global__ __launch_bounds__(512, 2) void ms1_main(
    const float* __restrict__ Y0,
    const float* __restrict__ bvec,
    const _Float16* __restrict__ B1h, const _Float16* __restrict__ B2h,
    float* __restrict__ out)
{
    __shared__ _Float16 lds[17408];   // 34816 B

    const int tid  = threadIdx.x;
    const int lane = tid & 63, w = tid >> 6;   // 8 waves; wave w: cols 32w..+31
    const int l15 = lane & 15, hi4 = lane >> 4;
    const size_t row0 = (size_t)blockIdx.x * 32;

    // per-lane B fragment offsets (halfs) within a tile's 8192-half block
    const int c0 = l15, c1 = 16 + l15;
    const int pb0 = (w << 10) + (c0 * 4 + (hi4 ^ ((c0 >> 1) & 3))) * 8;
    const int pb1 = (w << 10) + (c1 * 4 + (hi4 ^ ((c1 >> 1) & 3))) * 8;
    const size_t bsrc = (size_t)((w << 5) + (lane & 31)) * 64;  // bias gather

    float Ym[2][2][4], Zm[2][2][4];   // fp32 masters [mt][nt][q]

#pragma unroll
    for (int mt = 0; mt < 2; ++mt) {
#pragma unroll
        for (int nt = 0; nt < 2; ++nt) {
            const int n = (w << 5) + nt * 16 + l15;
#pragma unroll
            for (int q = 0; q < 4; ++q) {
                const int m = mt * 16 + hi4 * 4 + q;
                const size_t base = (row0 + m) * 512;
                const float y = Y0[base + n];
                const float z = Y0[base + 256 + n];
                Ym[mt][nt][q] = y; Zm[mt][nt][q] = z;
                lds[ST_Y + swz(m, n)] = (_Float16)y;
            }
        }
    }
    __syncthreads();   // init handoff; drains init loads -> vmcnt starts clean

    // prologue: issue B tiles 0,1 of (j=0, B1) into the 2 register sets
    f16x8 b0a, b0b, b1a, b1b;
    BLOAD(b0a, b0b, B1h, 0)
    BLOAD(b1a, b1b, B1h, 1)

    for (int j = 0; j < 64; ++j) {
        const _Float16* C1 = B1h + (size_t)j * 65536;
        const _Float16* C2 = B2h + (size_t)j * 65536;
        const int jn = (j < 63) ? j + 1 : 0;   // wrap: dead prefetch, in-bounds
        // Z += H*tanh(Y @ K^T + b[256:])   (A=Y; next B = B2 of same j)
        phase<false>(lds, ST_Y, ST_Z, C1, C2, bvec + 256 * 64 + j, Zm,
                     b0a, b0b, b1a, b1b, w, l15, hi4, pb0, pb1, bsrc);
        // Y += H*tanh(b[:256] - Z @ K)     (A=Z; next B = B1 of j+1)
        phase<true>(lds, ST_Z, ST_Y, C2, B1h + (size_t)jn * 65536,
                    bvec + j, Ym,
                    b0a, b0b, b1a, b1b, w, l15, hi4, pb0, pb1, bsrc);
    }

#pragma unroll
    for (int mt = 0; mt < 2; ++mt) {
#pragma unroll
        for (int nt = 0; nt < 2; ++nt) {
            const int n = (w << 5) + nt * 16 + l15;
#pragma unroll
            for (int q = 0; q < 4; ++q) {
                const int m = mt * 16 + hi4 * 4 + q;
                const size_t base = (row0 + m) * 512;
                out[base + n]       = Ym[mt][nt][q];
                out[base + 256 + n] = Zm[mt][nt][q];
            }
        }
    }
}

extern "C" void kernel_launch(void* const* d_in, const int* in_sizes, int n_in,
                              void* d_out, int out_size, void* d_ws, size_t ws_size,
                              hipStream_t stream) {
    (void)in_sizes; (void)n_in; (void)out_size;
    const float* Y0 = (const float*)d_in[0];
    const float* K  = (const float*)d_in[1];
    const float* b  = (const float*)d_in[2];

    const size_t ARR = (size_t)64 * 256 * 256;   // halfs per array
    if (ws_size < 2 * ARR * sizeof(_Float16)) return;

    _Float16* B1h = (_Float16*)d_ws;
    _Float16* B2h = B1h + ARR;

    prep_split<<<512, 256, 0, stream>>>(K, B1h, B2h);
    ms1_main<<<256, 512, 0, stream>>>(Y0, b, B1h, B2h, (float*)d_out);
}

// Round 14
// 305.210 us; speedup vs baseline: 1.0213x; 1.0213x over previous
//
#include <hip/hip_runtime.h>

// MS1: 64-layer reversible net, fused single-kernel recurrence.
//   Z += H*tanh(Y @ K_j^T + b_j[256:]);  Y += H*tanh(b_j[:256] - Z @ K_j)
// R14 = R12 (B global->reg depth-2 via inline-asm global_load_dwordx4, no LDS
// round-trip; only 16 async-pending VGPRs cross the barrier - R13's depth-4
// held 32 pending VGPRs through the high-pressure epilogue and faulted)
//     + R11's A depth-2 pipeline (3 rotating A sets, ds_read issued 2 kt
// ahead ~200cyc cover vs R12's depth-1 ~60cyc, counted lgkmcnt(4)).
// Ledgers (audited): vmcnt entry t0,t1(4) | KT0 WAITV(2) | KT1,2 WAITV(3) |
// KT3 WAITV(2) retires bias+t3 | KT4-7 WAITV(2) | exit 4 = entry.
// lgkm: pre-issue PK0,PK1; KT v issues PK v+2, WAITL(4); KT6:2 KT7:0.
// 256 blocks x 32 rows, 512 thr (8 waves); wave w owns cols 32w..32w+31,
// both m-tiles; fp16 GEMM inputs, fp32 masters in registers. LDS 34816 B.

typedef _Float16 f16x8 __attribute__((ext_vector_type(8)));
typedef _Float16 f16x2 __attribute__((ext_vector_type(2)));
typedef float    f32x4 __attribute__((ext_vector_type(4)));

#define H_STEP 0.015625f   // 1/64

// LDS layout in halfs (static 34816 B):
#define ST_Y   0          // Y hi: 0..8191
#define ST_Z   8192       // Z hi
#define BIASO  16384      // 8 waves x 64 f32 = 1024 halfs

__device__ __forceinline__ float fast_tanh(float x) {
    float xc = fminf(fmaxf(x, -9.0f), 9.0f);
    float t  = __builtin_amdgcn_exp2f(xc * 2.8853900817779268f); // 2x*log2(e)
    return (t - 1.0f) * __builtin_amdgcn_rcpf(t + 1.0f);
}

// state LDS index with XOR swizzle (16B-granular column rotation per row)
__device__ __forceinline__ int swz(int m, int k) {
    return (m << 8) + (k ^ ((m & 7) << 3));
}

__device__ __forceinline__ void gload4(const float* g, _Float16* l) {
    __builtin_amdgcn_global_load_lds(
        (const __attribute__((address_space(1))) unsigned int*)g,
        (__attribute__((address_space(3))) unsigned int*)l, 4, 0, 0);
}

// async 16B global->VGPR load; result valid only after our counted vmcnt wait
__device__ __forceinline__ f16x8 gload_async(const _Float16* p) {
    f16x8 r;
    asm volatile("global_load_dwordx4 %0, %1, off"
                 : "=v"(r) : "v"(p) : "memory");
    return r;
}

// ---------------- prep: K[a][b][j] -> fragment-ordered fp16 arrays ----------
// Layout: [j][kt][w 0..7][u 0..127][8 halfs]; unit u = c_local*4 + (chunk ^
// ((c_local>>1)&3)) holds B[col=32w+c_local][k=kt*32+chunk*8 ..+8].
// B1[n][k]=K[n][k][j] (Y@K^T);  B2[n][k]=K[k][n][j] (Z@K)
__global__ __launch_bounds__(256) void prep_split(
    const float* __restrict__ K,
    _Float16* __restrict__ B1h, _Float16* __restrict__ B2h)
{
    __shared__ float tile[32][33][9];
    const int a0 = (blockIdx.x & 7) << 5;
    const int b0 = ((blockIdx.x >> 3) & 7) << 5;
    const int j0 = (blockIdx.x >> 6) << 3;
    const int t = threadIdx.x;

    for (int idx = t; idx < 8192; idx += 256) {
        const int jj = idx & 7, bb = (idx >> 3) & 31, aa = idx >> 8;
        tile[aa][bb][jj] = K[((size_t)(a0 + aa) * 256 + (b0 + bb)) * 64 + (j0 + jj)];
    }
    __syncthreads();

    {
        const int w1 = a0 >> 5, kt = b0 >> 5;
        for (int idx = t; idx < 4096; idx += 256) {
            const int p = idx & 15, aa = (idx >> 4) & 31, jj = idx >> 9;
            const int kl = 2 * p, c = kl >> 3, e = kl & 7;
            const int u = aa * 4 + (c ^ ((aa >> 1) & 3));
            const size_t off = ((size_t)((j0 + jj) * 8 + kt)) * 8192 + w1 * 1024 + u * 8 + e;
            const f16x2 hv = {(_Float16)tile[aa][kl][jj], (_Float16)tile[aa][kl + 1][jj]};
            *(f16x2*)(B1h + off) = hv;
        }
    }
    {
        const int w2 = b0 >> 5, kt = a0 >> 5;
        for (int idx = t; idx < 4096; idx += 256) {
            const int p = idx & 15, bb = (idx >> 4) & 31, jj = idx >> 9;
            const int kl = 2 * p, c = kl >> 3, e = kl & 7;
            const int u = bb * 4 + (c ^ ((bb >> 1) & 3));
            const size_t off = ((size_t)((j0 + jj) * 8 + kt)) * 8192 + w2 * 1024 + u * 8 + e;
            const f16x2 hv = {(_Float16)tile[kl][bb][jj], (_Float16)tile[kl + 1][bb][jj]};
            *(f16x2*)(B2h + off) = hv;
        }
    }
}

#define MFMA16(A, B, C) __builtin_amdgcn_mfma_f32_16x16x32_f16((A), (B), (C), 0, 0, 0)
#define SBAR __builtin_amdgcn_sched_barrier(0)
#define WAITV(N) { asm volatile("s_waitcnt vmcnt(" #N ")" ::: "memory"); SBAR; }
#define WAITL(N) { asm volatile("s_waitcnt lgkmcnt(" #N ")" ::: "memory"); SBAR; }

// issue the 2 A ds_reads for k-tile PK into an A register set
#define LOADA(A0, A1, PK)                                                       \
    {                                                                           \
        const int k0_ = (PK) * 32 + hi4 * 8;                                    \
        A0 = *(const f16x8*)(lds + stA + swz(l15, k0_));                        \
        A1 = *(const f16x8*)(lds + stA + swz(16 + l15, k0_));                   \
    }

#define FMAS(A0, A1, B0, B1)                                                    \
    accH00 = MFMA16(A0, B0, accH00);                                            \
    accH01 = MFMA16(A0, B1, accH01);                                            \
    accH10 = MFMA16(A1, B0, accH10);                                            \
    accH11 = MFMA16(A1, B1, accH11);

// issue B tile T (halfs offset T*8192) from array SRC into a B register set
#define BLOAD(BA, BB, SRC, T)                                                   \
    BA = gload_async((SRC) + (T) * 8192 + pb0);                                 \
    BB = gload_async((SRC) + (T) * 8192 + pb1);

// one half-layer: 8 k-tiles; B in regs depth-2 (asm), A via LDS depth-2
template<bool NEG>
__device__ __forceinline__ void phase(
    _Float16* lds, const int stA, const int stO,
    const _Float16* __restrict__ Bc,   // this half-layer's B array (j base)
    const _Float16* __restrict__ Bn,   // next half-layer's B array
    const float* __restrict__ biasG,   // bvec + featbase*64 + j
    float (&M)[2][2][4],
    f16x8& b0a, f16x8& b0b, f16x8& b1a, f16x8& b1b,   // B sets (live cross-phase)
    const int w, const int l15, const int hi4,
    const int pb0, const int pb1, const size_t bsrc)
{
    f32x4 accH00 = {0.f,0.f,0.f,0.f}, accH01 = {0.f,0.f,0.f,0.f};
    f32x4 accH10 = {0.f,0.f,0.f,0.f}, accH11 = {0.f,0.f,0.f,0.f};

    f16x8 ax0, ax1, ay0, ay1, az0, az1;   // 3 rotating A sets (depth-2)
    LOADA(ax0, ax1, 0)
    LOADA(ay0, ay1, 1)

    // KT0: B t0(set0), A X(PK0)
    WAITV(2)
    LOADA(az0, az1, 2)
    WAITL(4)
    FMAS(ax0, ax1, b0a, b0b)
    BLOAD(b0a, b0b, Bc, 2)
    gload4(biasG + bsrc, lds + BIASO + (w << 7));
    // KT1: t1(set1), Y(PK1)
    WAITV(3)
    LOADA(ax0, ax1, 3)
    WAITL(4)
    FMAS(ay0, ay1, b1a, b1b)
    BLOAD(b1a, b1b, Bc, 3)
    // KT2: t2(set0), Z(PK2)
    WAITV(3)
    LOADA(ay0, ay1, 4)
    WAITL(4)
    FMAS(az0, az1, b0a, b0b)
    BLOAD(b0a, b0b, Bc, 4)
    // KT3: t3(set1), X(PK3)   (also retires bias)
    WAITV(2)
    LOADA(az0, az1, 5)
    WAITL(4)
    FMAS(ax0, ax1, b1a, b1b)
    BLOAD(b1a, b1b, Bc, 5)
    // KT4: t4(set0), Y(PK4)
    WAITV(2)
    LOADA(ax0, ax1, 6)
    WAITL(4)
    FMAS(ay0, ay1, b0a, b0b)
    BLOAD(b0a, b0b, Bc, 6)
    // KT5: t5(set1), Z(PK5)
    WAITV(2)
    LOADA(ay0, ay1, 7)
    WAITL(4)
    FMAS(az0, az1, b1a, b1b)
    BLOAD(b1a, b1b, Bc, 7)
    // KT6: t6(set0), X(PK6); tail prefetch -> next phase t0
    WAITV(2)
    WAITL(2)
    FMAS(ax0, ax1, b0a, b0b)
    BLOAD(b0a, b0b, Bn, 0)
    // KT7: t7(set1), Y(PK7); tail prefetch -> next phase t1
    WAITV(2)
    WAITL(0)
    FMAS(ay0, ay1, b1a, b1b)
    BLOAD(b1a, b1b, Bn, 1)

    // epilogue: bias from LDS, master += H*tanh(bias +/- acc), state hi to LDS
    const float* bp = (const float*)(lds + BIASO + (w << 7));
    const float bv0 = bp[l15], bv1 = bp[l15 + 16];

#pragma unroll
    for (int mt = 0; mt < 2; ++mt) {
#pragma unroll
        for (int nt = 0; nt < 2; ++nt) {
            const f32x4 s4 = (mt == 0) ? ((nt == 0) ? accH00 : accH01)
                                       : ((nt == 0) ? accH10 : accH11);
            const float bv = nt ? bv1 : bv0;
            const int n = (w << 5) + nt * 16 + l15;
#pragma unroll
            for (int q = 0; q < 4; ++q) {
                const float x = NEG ? (bv - s4[q]) : (s4[q] + bv);
                const float v = M[mt][nt][q] + H_STEP * fast_tanh(x);
                M[mt][nt][q] = v;
                const int m = mt * 16 + hi4 * 4 + q;
                lds[stO + swz(m, n)] = (_Float16)v;
            }
        }
    }
    // my state writes visible -> raw barrier (B prefetch vmcnt stays live)
    asm volatile("s_waitcnt lgkmcnt(0)" ::: "memory");
    __builtin_amdgcn_s_barrier();
    SBAR;
}

__global__ __launch_bounds__(512, 2) void ms1_main(
    const float* __restrict__ Y0,
    const float* __restrict__ bvec,
    const _Float16* __restrict__ B1h, const _Float16* __restrict__ B2h,
    float* __restrict__ out)
{
    __shared__ _Float16 lds[17408];   // 34816 B

    const int tid  = threadIdx.x;
    const int lane = tid & 63, w = tid >> 6;   // 8 waves; wave w: cols 32w..+31
    const int l15 = lane & 15, hi4 = lane >> 4;
    const size_t row0 = (size_t)blockIdx.x * 32;

    // per-lane B fragment offsets (halfs) within a tile's 8192-half block
    const int c0 = l15, c1 = 16 + l15;
    const int pb0 = (w << 10) + (c0 * 4 + (hi4 ^ ((c0 >> 1) & 3))) * 8;
    const int pb1 = (w << 10) + (c1 * 4 + (hi4 ^ ((c1 >> 1) & 3))) * 8;
    const size_t bsrc = (size_t)((w << 5) + (lane & 31)) * 64;  // bias gather

    float Ym[2][2][4], Zm[2][2][4];   // fp32 masters [mt][nt][q]

#pragma unroll
    for (int mt = 0; mt < 2; ++mt) {
#pragma unroll
        for (int nt = 0; nt < 2; ++nt) {
            const int n = (w << 5) + nt * 16 + l15;
#pragma unroll
            for (int q = 0; q < 4; ++q) {
                const int m = mt * 16 + hi4 * 4 + q;
                const size_t base = (row0 + m) * 512;
                const float y = Y0[base + n];
                const float z = Y0[base + 256 + n];
                Ym[mt][nt][q] = y; Zm[mt][nt][q] = z;
                lds[ST_Y + swz(m, n)] = (_Float16)y;
            }
        }
    }
    __syncthreads();   // init handoff; init loads drained -> vmcnt starts clean

    // prologue: issue B tiles 0,1 of (j=0, B1) into the 2 register sets
    f16x8 b0a, b0b, b1a, b1b;
    BLOAD(b0a, b0b, B1h, 0)
    BLOAD(b1a, b1b, B1h, 1)

    for (int j = 0; j < 64; ++j) {
        const _Float16* C1 = B1h + (size_t)j * 65536;
        const _Float16* C2 = B2h + (size_t)j * 65536;
        const int jn = (j < 63) ? j + 1 : 0;   // wrap: dead prefetch, in-bounds
        // Z += H*tanh(Y @ K^T + b[256:])   (A=Y; next B = B2 of same j)
        phase<false>(lds, ST_Y, ST_Z, C1, C2, bvec + 256 * 64 + j, Zm,
                     b0a, b0b, b1a, b1b, w, l15, hi4, pb0, pb1, bsrc);
        // Y += H*tanh(b[:256] - Z @ K)     (A=Z; next B = B1 of j+1)
        phase<true>(lds, ST_Z, ST_Y, C2, B1h + (size_t)jn * 65536,
                    bvec + j, Ym,
                    b0a, b0b, b1a, b1b, w, l15, hi4, pb0, pb1, bsrc);
    }

#pragma unroll
    for (int mt = 0; mt < 2; ++mt) {
#pragma unroll
        for (int nt = 0; nt < 2; ++nt) {
            const int n = (w << 5) + nt * 16 + l15;
#pragma unroll
            for (int q = 0; q < 4; ++q) {
                const int m = mt * 16 + hi4 * 4 + q;
                const size_t base = (row0 + m) * 512;
                out[base + n]       = Ym[mt][nt][q];
                out[base + 256 + n] = Zm[mt][nt][q];
            }
        }
    }
}

extern "C" void kernel_launch(void* const* d_in, const int* in_sizes, int n_in,
                              void* d_out, int out_size, void* d_ws, size_t ws_size,
                              hipStream_t stream) {
    (void)in_sizes; (void)n_in; (void)out_size;
    const float* Y0 = (const float*)d_in[0];
    const float* K  = (const float*)d_in[1];
    const float* b  = (const float*)d_in[2];

    const size_t ARR = (size_t)64 * 256 * 256;   // halfs per array
    if (ws_size < 2 * ARR * sizeof(_Float16)) return;

    _Float16* B1h = (_Float16*)d_ws;
    _Float16* B2h = B1h + ARR;

    prep_split<<<512, 256, 0, stream>>>(K, B1h, B2h);
    ms1_main<<<256, 512, 0, stream>>>(Y0, b, B1h, B2h, (float*)d_out);
}

// Round 15
// 283.876 us; speedup vs baseline: 1.0980x; 1.0752x over previous
//
#include <hip/hip_runtime.h>

// MS1: 64-layer reversible net, fused single-kernel recurrence.
//   Z += H*tanh(Y @ K_j^T + b_j[256:]);  Y += H*tanh(b_j[:256] - Z @ K_j)
// R15 = R11 verbatim (session best: 283 us). Plateau analysis: no pipe >50%
// of ceiling (L2 44%, LDS 43%, VALU 36%, MFMA 20%); the wall is the serial
// 128-phase recurrence at 1 block/CU (2 waves/SIMD), and occupancy cannot
// rise without >=2x traffic (L2-bound at ~490us). R12/R13/R14 (B->reg asm,
// deeper pipelines) all landed 305-311us or faulted; B-through-LDS-DMA with
// A depth-2 (this kernel) is the proven optimum of the explored space.
// Structure: 512 thr (8 waves), wave w owns cols 32w..32w+31, both m-tiles;
// fp16 GEMM inputs (fp32 masters in registers); B staged wave-locally via
// global_load_lds into 4 rotating 16KB buffers, exact counted vmcnt; A via
// 3 rotating register sets (ds_read 2 kt ahead, counted lgkmcnt); one raw
// s_barrier per phase. LDS 100352 B.

typedef _Float16 f16x8 __attribute__((ext_vector_type(8)));
typedef _Float16 f16x2 __attribute__((ext_vector_type(2)));
typedef float    f32x4 __attribute__((ext_vector_type(4)));

#define H_STEP 0.015625f   // 1/64

// LDS layout in halfs:
#define ST_Y   0          // Y hi: 0..8191
#define ST_Z   8192       // Z hi
#define BUF0   16384      // 4 buffers x 8192 halfs (16KB each)
#define BIASO  49152      // 8 waves x 64 f32 = 1024 halfs
// total 50176 halfs = 100352 bytes

__device__ __forceinline__ float fast_tanh(float x) {
    float xc = fminf(fmaxf(x, -9.0f), 9.0f);
    float t  = __builtin_amdgcn_exp2f(xc * 2.8853900817779268f); // 2x*log2(e)
    return (t - 1.0f) * __builtin_amdgcn_rcpf(t + 1.0f);
}

// state LDS index with XOR swizzle (16B-granular column rotation per row)
__device__ __forceinline__ int swz(int m, int k) {
    return (m << 8) + (k ^ ((m & 7) << 3));
}

__device__ __forceinline__ void gload16(const _Float16* g, _Float16* l) {
    __builtin_amdgcn_global_load_lds(
        (const __attribute__((address_space(1))) unsigned int*)g,
        (__attribute__((address_space(3))) unsigned int*)l, 16, 0, 0);
}
__device__ __forceinline__ void gload4(const float* g, _Float16* l) {
    __builtin_amdgcn_global_load_lds(
        (const __attribute__((address_space(1))) unsigned int*)g,
        (__attribute__((address_space(3))) unsigned int*)l, 4, 0, 0);
}

// ---------------- prep: K[a][b][j] -> DMA-tile-ordered fp16 arrays ----------
// Layout: [j][kt][w 0..7][u 0..127][8 halfs]; unit u = c_local*4 + (chunk ^
// ((c_local>>1)&3)) holds B[col=32w+c_local][k=kt*32+chunk*8 ..+8].
// B1[n][k]=K[n][k][j] (Y@K^T);  B2[n][k]=K[k][n][j] (Z@K)
__global__ __launch_bounds__(256) void prep_split(
    const float* __restrict__ K,
    _Float16* __restrict__ B1h, _Float16* __restrict__ B2h)
{
    __shared__ float tile[32][33][9];
    const int a0 = (blockIdx.x & 7) << 5;
    const int b0 = ((blockIdx.x >> 3) & 7) << 5;
    const int j0 = (blockIdx.x >> 6) << 3;
    const int t = threadIdx.x;

    for (int idx = t; idx < 8192; idx += 256) {
        const int jj = idx & 7, bb = (idx >> 3) & 31, aa = idx >> 8;
        tile[aa][bb][jj] = K[((size_t)(a0 + aa) * 256 + (b0 + bb)) * 64 + (j0 + jj)];
    }
    __syncthreads();

    {
        const int w1 = a0 >> 5, kt = b0 >> 5;
        for (int idx = t; idx < 4096; idx += 256) {
            const int p = idx & 15, aa = (idx >> 4) & 31, jj = idx >> 9;
            const int kl = 2 * p, c = kl >> 3, e = kl & 7;
            const int u = aa * 4 + (c ^ ((aa >> 1) & 3));
            const size_t off = ((size_t)((j0 + jj) * 8 + kt)) * 8192 + w1 * 1024 + u * 8 + e;
            const f16x2 hv = {(_Float16)tile[aa][kl][jj], (_Float16)tile[aa][kl + 1][jj]};
            *(f16x2*)(B1h + off) = hv;
        }
    }
    {
        const int w2 = b0 >> 5, kt = a0 >> 5;
        for (int idx = t; idx < 4096; idx += 256) {
            const int p = idx & 15, bb = (idx >> 4) & 31, jj = idx >> 9;
            const int kl = 2 * p, c = kl >> 3, e = kl & 7;
            const int u = bb * 4 + (c ^ ((bb >> 1) & 3));
            const size_t off = ((size_t)((j0 + jj) * 8 + kt)) * 8192 + w2 * 1024 + u * 8 + e;
            const f16x2 hv = {(_Float16)tile[kl][bb][jj], (_Float16)tile[kl + 1][bb][jj]};
            *(f16x2*)(B2h + off) = hv;
        }
    }
}

#define MFMA16(A, B, C) __builtin_amdgcn_mfma_f32_16x16x32_f16((A), (B), (C), 0, 0, 0)
#define SBAR __builtin_amdgcn_sched_barrier(0)
#define WAITV(N) { asm volatile("s_waitcnt vmcnt(" #N ")" ::: "memory"); SBAR; }
#define WAITL(N) { asm volatile("s_waitcnt lgkmcnt(" #N ")" ::: "memory"); SBAR; }

// issue the 4 ds_reads for k-tile PK into a register set
#define LOADF(A0, A1, B0, B1, PK)                                               \
    {                                                                           \
        const int k0_ = (PK) * 32 + hi4 * 8;                                    \
        const _Float16* bb_ = lds + BUF0 + ((PK) & 3) * 8192 + bfw;             \
        B0 = *(const f16x8*)(bb_ + bf0);                                        \
        B1 = *(const f16x8*)(bb_ + bf1);                                        \
        A0 = *(const f16x8*)(lds + stA + swz(l15, k0_));                        \
        A1 = *(const f16x8*)(lds + stA + swz(16 + l15, k0_));                   \
    }

// DMA tile T (0..11; >=8 -> next phase's tile T-8) into buf T&3
#define DMAT(T)                                                                 \
    {                                                                           \
        const _Float16* sb_ = ((T) < 8) ? Bc : Bn;                              \
        _Float16* db_ = lds + BUF0 + ((T) & 3) * 8192 + gdst;                   \
        gload16(sb_ + ((T) & 7) * 8192 + gsrc,       db_);                      \
        gload16(sb_ + ((T) & 7) * 8192 + gsrc + 512, db_ + 512);                \
    }

#define FMAS(A0, A1, B0, B1)                                                    \
    accH00 = MFMA16(A0, B0, accH00);                                            \
    accH01 = MFMA16(A0, B1, accH01);                                            \
    accH10 = MFMA16(A1, B0, accH10);                                            \
    accH11 = MFMA16(A1, B1, accH11);

// one half-layer: 8 k-tiles, 2-deep read pipeline + epilogue + raw barrier
template<bool NEG>
__device__ __forceinline__ void phase(
    _Float16* lds, const int stA, const int stO,
    const _Float16* __restrict__ Bc,   // this half-layer's B array (j base)
    const _Float16* __restrict__ Bn,   // next half-layer's B array
    const float* __restrict__ biasG,   // bvec + featbase*64 + j
    float (&M)[2][2][4],
    const int w, const int l15, const int hi4,
    const int bfw, const int bf0, const int bf1,
    const int gsrc, const int gdst, const size_t bsrc)
{
    f32x4 accH00 = {0.f,0.f,0.f,0.f}, accH01 = {0.f,0.f,0.f,0.f};
    f32x4 accH10 = {0.f,0.f,0.f,0.f}, accH11 = {0.f,0.f,0.f,0.f};

    f16x8 a00,a01,b00,b01;   // S0
    f16x8 a10,a11,b10,b11;   // S1
    f16x8 a20,a21,b20,b21;   // S2

    // entry: 8 DMA ops outstanding -> wait to 4: tiles 0,1 resident
    WAITV(4)
    LOADF(a00,a01,b00,b01, 0)
    LOADF(a10,a11,b10,b11, 1)

    // KT0
    WAITV(2) WAITL(4)
    gload4(biasG + bsrc, lds + BIASO + (w << 7));
    DMAT(4)  LOADF(a20,a21,b20,b21, 2)  FMAS(a00,a01,b00,b01)
    // KT1
    WAITV(3) WAITL(4)
    DMAT(5)  LOADF(a00,a01,b00,b01, 3)  FMAS(a10,a11,b10,b11)
    // KT2
    WAITV(2) WAITL(4)
    DMAT(6)  LOADF(a10,a11,b10,b11, 4)  FMAS(a20,a21,b20,b21)
    // KT3
    WAITV(2) WAITL(4)
    DMAT(7)  LOADF(a20,a21,b20,b21, 5)  FMAS(a00,a01,b00,b01)
    // KT4
    WAITV(2) WAITL(4)
    DMAT(8)  LOADF(a00,a01,b00,b01, 6)  FMAS(a10,a11,b10,b11)
    // KT5
    WAITV(2) WAITL(4)
    DMAT(9)  LOADF(a10,a11,b10,b11, 7)  FMAS(a20,a21,b20,b21)
    // KT6 (taper: no new reads)
    WAITL(4)
    DMAT(10) FMAS(a00,a01,b00,b01)
    // KT7
    WAITL(0)
    DMAT(11) FMAS(a10,a11,b10,b11)

    // epilogue: bias from LDS, master += H*tanh(bias +/- acc), state hi to LDS
    const float* bp = (const float*)(lds + BIASO + (w << 7));
    const float bv0 = bp[l15], bv1 = bp[l15 + 16];

#pragma unroll
    for (int mt = 0; mt < 2; ++mt) {
#pragma unroll
        for (int nt = 0; nt < 2; ++nt) {
            const f32x4 s4 = (mt == 0) ? ((nt == 0) ? accH00 : accH01)
                                       : ((nt == 0) ? accH10 : accH11);
            const float bv = nt ? bv1 : bv0;
            const int n = (w << 5) + nt * 16 + l15;
#pragma unroll
            for (int q = 0; q < 4; ++q) {
                const float x = NEG ? (bv - s4[q]) : (s4[q] + bv);
                const float v = M[mt][nt][q] + H_STEP * fast_tanh(x);
                M[mt][nt][q] = v;
                const int m = mt * 16 + hi4 * 4 + q;
                lds[stO + swz(m, n)] = (_Float16)v;
            }
        }
    }
    // my state writes done -> raw barrier (DMA vmcnt stays live across it)
    asm volatile("s_waitcnt lgkmcnt(0)" ::: "memory");
    __builtin_amdgcn_s_barrier();
    SBAR;
}

__global__ __launch_bounds__(512, 2) void ms1_main(
    const float* __restrict__ Y0,
    const float* __restrict__ bvec,
    const _Float16* __restrict__ B1h, const _Float16* __restrict__ B2h,
    float* __restrict__ out)
{
    extern __shared__ _Float16 lds[];   // 50176 halfs = 100352 B

    const int tid  = threadIdx.x;
    const int lane = tid & 63, w = tid >> 6;   // 8 waves; wave w: cols 32w..+31
    const int l15 = lane & 15, hi4 = lane >> 4;
    const size_t row0 = (size_t)blockIdx.x * 32;

    const int bfw = w << 10;
    const int c0 = l15, c1 = 16 + l15;
    const int bf0 = (c0 * 4 + (hi4 ^ ((c0 >> 1) & 3))) * 8;
    const int bf1 = (c1 * 4 + (hi4 ^ ((c1 >> 1) & 3))) * 8;
    const int gsrc = (w << 10) + lane * 8;
    const int gdst = (w << 10);
    const size_t bsrc = (size_t)((w << 5) + (lane & 31)) * 64;  // bias gather

    float Ym[2][2][4], Zm[2][2][4];   // fp32 masters [mt][nt][q]

#pragma unroll
    for (int mt = 0; mt < 2; ++mt) {
#pragma unroll
        for (int nt = 0; nt < 2; ++nt) {
            const int n = (w << 5) + nt * 16 + l15;
#pragma unroll
            for (int q = 0; q < 4; ++q) {
                const int m = mt * 16 + hi4 * 4 + q;
                const size_t base = (row0 + m) * 512;
                const float y = Y0[base + n];
                const float z = Y0[base + 256 + n];
                Ym[mt][nt][q] = y; Zm[mt][nt][q] = z;
                lds[ST_Y + swz(m, n)] = (_Float16)y;
            }
        }
    }
    __syncthreads();   // init handoff (no DMAs in flight yet)

    // prologue: DMA tiles 0..3 of (j=0, B1) into bufs 0..3 (8 ops in flight)
#pragma unroll
    for (int t0 = 0; t0 < 4; ++t0) {
        _Float16* db = lds + BUF0 + t0 * 8192 + gdst;
        gload16(B1h + t0 * 8192 + gsrc,       db);
        gload16(B1h + t0 * 8192 + gsrc + 512, db + 512);
    }

    for (int j = 0; j < 64; ++j) {
        const _Float16* C1 = B1h + (size_t)j * 65536;
        const _Float16* C2 = B2h + (size_t)j * 65536;
        const int jn = (j < 63) ? j + 1 : 0;   // wrap: dead prefetch, in-bounds
        // Z += H*tanh(Y @ K^T + b[256:])   (A=Y; next B = B2 of same j)
        phase<false>(lds, ST_Y, ST_Z, C1, C2, bvec + 256 * 64 + j, Zm,
                     w, l15, hi4, bfw, bf0, bf1, gsrc, gdst, bsrc);
        // Y += H*tanh(b[:256] - Z @ K)     (A=Z; next B = B1 of j+1)
        phase<true>(lds, ST_Z, ST_Y, C2, B1h + (size_t)jn * 65536,
                    bvec + j, Ym,
                    w, l15, hi4, bfw, bf0, bf1, gsrc, gdst, bsrc);
    }

#pragma unroll
    for (int mt = 0; mt < 2; ++mt) {
#pragma unroll
        for (int nt = 0; nt < 2; ++nt) {
            const int n = (w << 5) + nt * 16 + l15;
#pragma unroll
            for (int q = 0; q < 4; ++q) {
                const int m = mt * 16 + hi4 * 4 + q;
                const size_t base = (row0 + m) * 512;
                out[base + n]       = Ym[mt][nt][q];
                out[base + 256 + n] = Zm[mt][nt][q];
            }
        }
    }
}

extern "C" void kernel_launch(void* const* d_in, const int* in_sizes, int n_in,
                              void* d_out, int out_size, void* d_ws, size_t ws_size,
                              hipStream_t stream) {
    (void)in_sizes; (void)n_in; (void)out_size;
    const float* Y0 = (const float*)d_in[0];
    const float* K  = (const float*)d_in[1];
    const float* b  = (const float*)d_in[2];

    const size_t ARR = (size_t)64 * 256 * 256;   // halfs per array
    if (ws_size < 2 * ARR * sizeof(_Float16)) return;

    _Float16* B1h = (_Float16*)d_ws;
    _Float16* B2h = B1h + ARR;

    hipFuncSetAttribute((const void*)ms1_main,
                        hipFuncAttributeMaxDynamicSharedMemorySize, 100352);

    prep_split<<<512, 256, 0, stream>>>(K, B1h, B2h);
    ms1_main<<<256, 512, 100352, stream>>>(Y0, b, B1h, B2h, (float*)d_out);
}